// Round 24
// baseline (301.810 us; speedup 1.0000x reference)
//
#include <hip/hip_runtime.h>
#include <hip/hip_bf16.h>
#include <limits.h>

#define N 16384
#define D 128
#define RS 16                        // row splits (1024 rows each)
#define CT 32                        // col tiles (N / 512)
#define ROWS_PER_SPLIT (N / RS)      // 1024
#define ITERS (ROWS_PER_SPLIT / 32)  // 32 iterations of 32 rows

typedef __attribute__((ext_vector_type(4))) int i32x4;
typedef __attribute__((ext_vector_type(16))) int i32x16;

// ---------------- Kernel A: quantize targets -> int8 (scale 127), row-major ----------------
__global__ __launch_bounds__(256) void knorm(const float* __restrict__ t,
                                             char* __restrict__ bnq) {
    const int lane = threadIdx.x & 63;
    const int row  = blockIdx.x * 4 + (threadIdx.x >> 6);
    const float2 v = *(const float2*)(t + (size_t)row * D + lane * 2);
    float ss = v.x * v.x + v.y * v.y;
#pragma unroll
    for (int m = 1; m <= 32; m <<= 1) ss += __shfl_xor(ss, m, 64);
    const float s127 = rsqrtf(ss) * 127.0f;
    char2 o;
    o.x = (char)__float2int_rn(v.x * s127);
    o.y = (char)__float2int_rn(v.y * s127);
    *(char2*)(bnq + (size_t)row * 128 + lane * 2) = o;
}

// ---------------- Kernel B: fused i8 bn @ bn^T (32x32x32) + EXACT-row argmax ----------------
// R23 core with QUAD-buffered A-prefetch (the R10 lever, never applied to i8):
// prefetch distance 4 iterations covers L2/L3 load latency at 2 waves/SIMD.
// +32 regs (fC,fD) -> ~156 total, well under the 256 budget of (256,2).
__global__ __launch_bounds__(256, 2) void kargmax(const char* __restrict__ bnq,
                                                  int* __restrict__ pval) {
    const int tid  = threadIdx.x;
    const int lane = tid & 63;
    const int w    = tid >> 6;
    const int b    = blockIdx.x;
    const int s    = (b & 7) * 2 + ((b >> 3) & 1);   // 2 splits per XCD
    const int ct   = b >> 4;                          // 0..31
    const int j0w  = ct * 512 + w * 128;
    const int rbase = s * ROWS_PER_SPLIT;

    const int cl = lane & 31;      // row/col within 32
    const int hi = lane >> 5;      // k-half
    const int rloc = cl - 4 * hi;  // diag helper: diag when rloc == (r&3)+8*(r>>2)

    // persistent B fragments: 128 cols x 128 K, i8 (4 col-tiles x 4 K-steps, 64 VGPRs)
    i32x4 fb[4][4];
#pragma unroll
    for (int c4 = 0; c4 < 4; ++c4)
#pragma unroll
        for (int ks = 0; ks < 4; ++ks)
            fb[c4][ks] = *(const i32x4*)(bnq + (size_t)(j0w + c4 * 32 + cl) * 128 +
                                         ks * 32 + hi * 16);

    const char* aptr = bnq + (size_t)(rbase + cl) * 128 + hi * 16;

    int mv[4];
#pragma unroll
    for (int c4 = 0; c4 < 4; ++c4) mv[c4] = INT_MIN;

    const i32x16 z16 = {0,0,0,0,0,0,0,0,0,0,0,0,0,0,0,0};
    i32x4 fA[4], fB[4], fC[4], fD[4];

#define LOADF(buf, itv) do {                                  \
    const char* p_ = aptr + (size_t)(itv) * 4096;             \
    buf[0] = *(const i32x4*)(p_);                             \
    buf[1] = *(const i32x4*)(p_ + 32);                        \
    buf[2] = *(const i32x4*)(p_ + 64);                        \
    buf[3] = *(const i32x4*)(p_ + 96); } while (0)

#define COMPUTEF(buf, itv) do {                                                             \
    const int r0_ = rbase + (itv) * 32;                                                     \
    const bool dg_ = ((unsigned)(r0_ - j0w) < 128u);                                        \
    i32x16 acc[4];                                                                          \
    __builtin_amdgcn_s_setprio(1);                                                          \
    _Pragma("unroll")                                                                       \
    for (int c4 = 0; c4 < 4; ++c4)                                                          \
        acc[c4] = __builtin_amdgcn_mfma_i32_32x32x32_i8(buf[0], fb[c4][0], z16, 0, 0, 0);   \
    _Pragma("unroll")                                                                       \
    for (int ks = 1; ks < 4; ++ks) {                                                        \
        _Pragma("unroll")                                                                   \
        for (int c4 = 0; c4 < 4; ++c4)                                                      \
            acc[c4] = __builtin_amdgcn_mfma_i32_32x32x32_i8(buf[ks], fb[c4][ks],            \
                                                            acc[c4], 0, 0, 0);              \
    }                                                                                       \
    __builtin_amdgcn_s_setprio(0);                                                          \
    if (dg_) {                                                                              \
        _Pragma("unroll")                                                                   \
        for (int c4 = 0; c4 < 4; ++c4)                                                      \
            if (r0_ == j0w + c4 * 32) {                                                     \
                _Pragma("unroll")                                                           \
                for (int r = 0; r < 16; ++r)                                                \
                    if (rloc == ((r & 3) + 8 * (r >> 2))) acc[c4][r] = -(1 << 21);          \
            }                                                                               \
    }                                                                                       \
    const int ib_ = (itv) * 32 + 4 * hi;                                                    \
    _Pragma("unroll")                                                                       \
    for (int c4 = 0; c4 < 4; ++c4) {                                                        \
        int p[16];                                                                          \
        _Pragma("unroll")                                                                   \
        for (int r = 0; r < 16; ++r)                                                        \
            p[r] = (int)(((unsigned)acc[c4][r] << 10)) +                                    \
                   (ib_ + (r & 3) + 8 * (r >> 2));                                          \
        const int a0 = max(max(p[0],  p[1]),  p[2]);                                        \
        const int a1 = max(max(p[3],  p[4]),  p[5]);                                        \
        const int a2 = max(max(p[6],  p[7]),  p[8]);                                        \
        const int a3 = max(max(p[9],  p[10]), p[11]);                                       \
        const int a4 = max(max(p[12], p[13]), p[14]);                                       \
        const int b0 = max(max(a0, a1), a2);                                                \
        const int b1 = max(max(a3, a4), p[15]);                                             \
        mv[c4] = max(mv[c4], max(b0, b1));                                                  \
    }                                                                                       \
    } while (0)

    LOADF(fA, 0);
    LOADF(fB, 1);
    LOADF(fC, 2);
    LOADF(fD, 3);
    for (int it4 = 0; it4 < ITERS; it4 += 4) {
        COMPUTEF(fA, it4);     LOADF(fA, it4 + 4);   // overshoot (<=16KB) -> pval pad, unused
        COMPUTEF(fB, it4 + 1); LOADF(fB, it4 + 5);
        COMPUTEF(fC, it4 + 2); LOADF(fC, it4 + 6);
        COMPUTEF(fD, it4 + 3); LOADF(fD, it4 + 7);
    }
#undef LOADF
#undef COMPUTEF

    // lanes l and l+32 hold different row-halves of each column: one max merges them
#pragma unroll
    for (int c4 = 0; c4 < 4; ++c4) {
        int v = mv[c4];
        v = max(v, __shfl_xor(v, 32, 64));
        if (lane < 32)
            pval[(size_t)(j0w + c4 * 32 + cl) * RS + s] = v;
    }
}

// ---------------- Kernel C: merge splits (coalesced), hinge loss ----------------
__global__ __launch_bounds__(256) void kloss(const float* __restrict__ q,
                                             const float* __restrict__ t,
                                             const int* __restrict__ pval,
                                             float* __restrict__ bsum) {
    const int j    = blockIdx.x * 4 + (threadIdx.x >> 6);
    const int lane = threadIdx.x & 63;

    // merge the RS split winners — pval[j][s] is one contiguous 64B line
    int v = INT_MIN;
    int sidx = 0;
    if (lane < RS) { v = pval[(size_t)j * RS + lane]; sidx = lane; }
#pragma unroll
    for (int m = 1; m <= 8; m <<= 1) {
        const int ov = __shfl_xor(v, m, 64);
        const int os = __shfl_xor(sidx, m, 64);
        if (ov > v || (ov == v && os < sidx)) { v = ov; sidx = os; }
    }
    v = __shfl(v, 0, 64);
    sidx = __shfl(sidx, 0, 64);
    const int c = sidx * ROWS_PER_SPLIT + (v & 1023);   // exact winner row

    const float2 qv = *(const float2*)(q + (size_t)j * D + lane * 2);
    const float2 tv = *(const float2*)(t + (size_t)j * D + lane * 2);
    const float2 wv = *(const float2*)(t + (size_t)c * D + lane * 2);
    float qq = qv.x * qv.x + qv.y * qv.y;
    float tt = tv.x * tv.x + tv.y * tv.y;
    float ww = wv.x * wv.x + wv.y * wv.y;
    float qt = qv.x * tv.x + qv.y * tv.y;
    float qw = qv.x * wv.x + qv.y * wv.y;
#pragma unroll
    for (int m = 1; m <= 32; m <<= 1) {
        qq += __shfl_xor(qq, m, 64);
        tt += __shfl_xor(tt, m, 64);
        ww += __shfl_xor(ww, m, 64);
        qt += __shfl_xor(qt, m, 64);
        qw += __shfl_xor(qw, m, 64);
    }
    const float pos = qt * rsqrtf(qq * tt);
    const float neg = qw * rsqrtf(qq * ww);
    const float l = fmaxf(0.f, 1.0f - pos + neg);

    __shared__ float ls[4];
    if (lane == 0) ls[threadIdx.x >> 6] = l;
    __syncthreads();
    if (threadIdx.x == 0) bsum[blockIdx.x] = ls[0] + ls[1] + ls[2] + ls[3];
}

// ---------------- Kernel D: deterministic final mean ----------------
__global__ __launch_bounds__(256) void kfinal(const float* __restrict__ bsum,
                                              float* __restrict__ out) {
    float sum = 0.f;
    for (int i = threadIdx.x; i < N / 4; i += 256) sum += bsum[i];
#pragma unroll
    for (int m = 1; m <= 32; m <<= 1) sum += __shfl_xor(sum, m, 64);
    __shared__ float ws2[4];
    if ((threadIdx.x & 63) == 0) ws2[threadIdx.x >> 6] = sum;
    __syncthreads();
    if (threadIdx.x == 0) out[0] = (ws2[0] + ws2[1] + ws2[2] + ws2[3]) * (1.0f / N);
}

extern "C" void kernel_launch(void* const* d_in, const int* in_sizes, int n_in,
                              void* d_out, int out_size, void* d_ws, size_t ws_size,
                              hipStream_t stream) {
    const float* q = (const float*)d_in[0];
    const float* t = (const float*)d_in[1];
    char* ws = (char*)d_ws;

    char* bnq = ws;                                                    // 2 MB (must stay first)
    int*  pval = (int*)(ws + (size_t)N * 128);                         // 1 MB (also overshoot pad)
    float* bsum = (float*)(ws + (size_t)N * 128 + (size_t)RS * N * 4); // 16 KB

    knorm<<<dim3(N / 4), dim3(256), 0, stream>>>(t, bnq);
    kargmax<<<dim3(CT * RS), dim3(256), 0, stream>>>(bnq, pval);
    kloss<<<dim3(N / 4), dim3(256), 0, stream>>>(q, t, pval, bsum);
    kfinal<<<dim3(1), dim3(256), 0, stream>>>(bsum, (float*)d_out);
}

// Round 25
// 62.371 us; speedup vs baseline: 4.8389x; 4.8389x over previous
//
#include <hip/hip_runtime.h>
#include <hip/hip_bf16.h>
#include <limits.h>

#define N 16384
#define D 128
#define RS 16                        // row splits (1024 rows each)
#define CT 32                        // col tiles (N / 512)
#define ROWS_PER_SPLIT (N / RS)      // 1024
#define ITERS (ROWS_PER_SPLIT / 32)  // 32 iterations of 32 rows

typedef __attribute__((ext_vector_type(4))) int i32x4;
typedef __attribute__((ext_vector_type(16))) int i32x16;

// ---------------- Kernel A: quantize targets -> int8 (scale 127), row-major ----------------
__global__ __launch_bounds__(256) void knorm(const float* __restrict__ t,
                                             char* __restrict__ bnq) {
    const int lane = threadIdx.x & 63;
    const int row  = blockIdx.x * 4 + (threadIdx.x >> 6);
    const float2 v = *(const float2*)(t + (size_t)row * D + lane * 2);
    float ss = v.x * v.x + v.y * v.y;
#pragma unroll
    for (int m = 1; m <= 32; m <<= 1) ss += __shfl_xor(ss, m, 64);
    const float s127 = rsqrtf(ss) * 127.0f;
    char2 o;
    o.x = (char)__float2int_rn(v.x * s127);
    o.y = (char)__float2int_rn(v.y * s127);
    *(char2*)(bnq + (size_t)row * 128 + lane * 2) = o;
}

// ---------------- Kernel B: fused i8 bn @ bn^T (32x32x32) + EXACT-row argmax ----------------
// Final configuration (R23): 512 blocks x 4 waves, double-buffered register
// A-stream, no LDS/barriers, XCD-local decode. int sims fit 21 bits -> pack
// (sim<<10)|local_row; diag acc = -(1<<21); max3-shaped reduction tree.
// Output pval[j][s] transposed; winner row = s*1024 + (pval&1023).
// Register wall (5x measured): any added state (deeper prefetch, wider frames)
// spills at this tile size — do not grow.
__global__ __launch_bounds__(256, 2) void kargmax(const char* __restrict__ bnq,
                                                  int* __restrict__ pval) {
    const int tid  = threadIdx.x;
    const int lane = tid & 63;
    const int w    = tid >> 6;
    const int b    = blockIdx.x;
    const int s    = (b & 7) * 2 + ((b >> 3) & 1);   // 2 splits per XCD
    const int ct   = b >> 4;                          // 0..31
    const int j0w  = ct * 512 + w * 128;
    const int rbase = s * ROWS_PER_SPLIT;

    const int cl = lane & 31;      // row/col within 32
    const int hi = lane >> 5;      // k-half
    const int rloc = cl - 4 * hi;  // diag helper: diag when rloc == (r&3)+8*(r>>2)

    // persistent B fragments: 128 cols x 128 K, i8 (4 col-tiles x 4 K-steps, 64 VGPRs)
    i32x4 fb[4][4];
#pragma unroll
    for (int c4 = 0; c4 < 4; ++c4)
#pragma unroll
        for (int ks = 0; ks < 4; ++ks)
            fb[c4][ks] = *(const i32x4*)(bnq + (size_t)(j0w + c4 * 32 + cl) * 128 +
                                         ks * 32 + hi * 16);

    const char* aptr = bnq + (size_t)(rbase + cl) * 128 + hi * 16;

    int mv[4];
#pragma unroll
    for (int c4 = 0; c4 < 4; ++c4) mv[c4] = INT_MIN;

    const i32x16 z16 = {0,0,0,0,0,0,0,0,0,0,0,0,0,0,0,0};
    i32x4 fA[4], fB[4];

#define LOADF(buf, itv) do {                                  \
    const char* p_ = aptr + (size_t)(itv) * 4096;             \
    buf[0] = *(const i32x4*)(p_);                             \
    buf[1] = *(const i32x4*)(p_ + 32);                        \
    buf[2] = *(const i32x4*)(p_ + 64);                        \
    buf[3] = *(const i32x4*)(p_ + 96); } while (0)

#define COMPUTEF(buf, itv) do {                                                             \
    const int r0_ = rbase + (itv) * 32;                                                     \
    const bool dg_ = ((unsigned)(r0_ - j0w) < 128u);                                        \
    i32x16 acc[4];                                                                          \
    __builtin_amdgcn_s_setprio(1);                                                          \
    _Pragma("unroll")                                                                       \
    for (int c4 = 0; c4 < 4; ++c4)                                                          \
        acc[c4] = __builtin_amdgcn_mfma_i32_32x32x32_i8(buf[0], fb[c4][0], z16, 0, 0, 0);   \
    _Pragma("unroll")                                                                       \
    for (int ks = 1; ks < 4; ++ks) {                                                        \
        _Pragma("unroll")                                                                   \
        for (int c4 = 0; c4 < 4; ++c4)                                                      \
            acc[c4] = __builtin_amdgcn_mfma_i32_32x32x32_i8(buf[ks], fb[c4][ks],            \
                                                            acc[c4], 0, 0, 0);              \
    }                                                                                       \
    __builtin_amdgcn_s_setprio(0);                                                          \
    if (dg_) {                                                                              \
        _Pragma("unroll")                                                                   \
        for (int c4 = 0; c4 < 4; ++c4)                                                      \
            if (r0_ == j0w + c4 * 32) {                                                     \
                _Pragma("unroll")                                                           \
                for (int r = 0; r < 16; ++r)                                                \
                    if (rloc == ((r & 3) + 8 * (r >> 2))) acc[c4][r] = -(1 << 21);          \
            }                                                                               \
    }                                                                                       \
    const int ib_ = (itv) * 32 + 4 * hi;                                                    \
    _Pragma("unroll")                                                                       \
    for (int c4 = 0; c4 < 4; ++c4) {                                                        \
        int p[16];                                                                          \
        _Pragma("unroll")                                                                   \
        for (int r = 0; r < 16; ++r)                                                        \
            p[r] = (int)(((unsigned)acc[c4][r] << 10)) +                                    \
                   (ib_ + (r & 3) + 8 * (r >> 2));                                          \
        const int a0 = max(max(p[0],  p[1]),  p[2]);                                        \
        const int a1 = max(max(p[3],  p[4]),  p[5]);                                        \
        const int a2 = max(max(p[6],  p[7]),  p[8]);                                        \
        const int a3 = max(max(p[9],  p[10]), p[11]);                                       \
        const int a4 = max(max(p[12], p[13]), p[14]);                                       \
        const int b0 = max(max(a0, a1), a2);                                                \
        const int b1 = max(max(a3, a4), p[15]);                                             \
        mv[c4] = max(mv[c4], max(b0, b1));                                                  \
    }                                                                                       \
    } while (0)

    LOADF(fA, 0);
    LOADF(fB, 1);
    for (int it2 = 0; it2 < ITERS; it2 += 2) {
        COMPUTEF(fA, it2);     LOADF(fA, it2 + 2);   // overshoot -> pval pad, unused
        COMPUTEF(fB, it2 + 1); LOADF(fB, it2 + 3);
    }
#undef LOADF
#undef COMPUTEF

    // lanes l and l+32 hold different row-halves of each column: one max merges them
#pragma unroll
    for (int c4 = 0; c4 < 4; ++c4) {
        int v = mv[c4];
        v = max(v, __shfl_xor(v, 32, 64));
        if (lane < 32)
            pval[(size_t)(j0w + c4 * 32 + cl) * RS + s] = v;
    }
}

// ---------------- Kernel C: merge splits (coalesced), hinge loss ----------------
__global__ __launch_bounds__(256) void kloss(const float* __restrict__ q,
                                             const float* __restrict__ t,
                                             const int* __restrict__ pval,
                                             float* __restrict__ bsum) {
    const int j    = blockIdx.x * 4 + (threadIdx.x >> 6);
    const int lane = threadIdx.x & 63;

    // merge the RS split winners — pval[j][s] is one contiguous 64B line
    int v = INT_MIN;
    int sidx = 0;
    if (lane < RS) { v = pval[(size_t)j * RS + lane]; sidx = lane; }
#pragma unroll
    for (int m = 1; m <= 8; m <<= 1) {
        const int ov = __shfl_xor(v, m, 64);
        const int os = __shfl_xor(sidx, m, 64);
        if (ov > v || (ov == v && os < sidx)) { v = ov; sidx = os; }
    }
    v = __shfl(v, 0, 64);
    sidx = __shfl(sidx, 0, 64);
    const int c = sidx * ROWS_PER_SPLIT + (v & 1023);   // exact winner row

    const float2 qv = *(const float2*)(q + (size_t)j * D + lane * 2);
    const float2 tv = *(const float2*)(t + (size_t)j * D + lane * 2);
    const float2 wv = *(const float2*)(t + (size_t)c * D + lane * 2);
    float qq = qv.x * qv.x + qv.y * qv.y;
    float tt = tv.x * tv.x + tv.y * tv.y;
    float ww = wv.x * wv.x + wv.y * wv.y;
    float qt = qv.x * tv.x + qv.y * tv.y;
    float qw = qv.x * wv.x + qv.y * wv.y;
#pragma unroll
    for (int m = 1; m <= 32; m <<= 1) {
        qq += __shfl_xor(qq, m, 64);
        tt += __shfl_xor(tt, m, 64);
        ww += __shfl_xor(ww, m, 64);
        qt += __shfl_xor(qt, m, 64);
        qw += __shfl_xor(qw, m, 64);
    }
    const float pos = qt * rsqrtf(qq * tt);
    const float neg = qw * rsqrtf(qq * ww);
    const float l = fmaxf(0.f, 1.0f - pos + neg);

    __shared__ float ls[4];
    if (lane == 0) ls[threadIdx.x >> 6] = l;
    __syncthreads();
    if (threadIdx.x == 0) bsum[blockIdx.x] = ls[0] + ls[1] + ls[2] + ls[3];
}

// ---------------- Kernel D: deterministic final mean ----------------
__global__ __launch_bounds__(256) void kfinal(const float* __restrict__ bsum,
                                              float* __restrict__ out) {
    float sum = 0.f;
    for (int i = threadIdx.x; i < N / 4; i += 256) sum += bsum[i];
#pragma unroll
    for (int m = 1; m <= 32; m <<= 1) sum += __shfl_xor(sum, m, 64);
    __shared__ float ws2[4];
    if ((threadIdx.x & 63) == 0) ws2[threadIdx.x >> 6] = sum;
    __syncthreads();
    if (threadIdx.x == 0) out[0] = (ws2[0] + ws2[1] + ws2[2] + ws2[3]) * (1.0f / N);
}

extern "C" void kernel_launch(void* const* d_in, const int* in_sizes, int n_in,
                              void* d_out, int out_size, void* d_ws, size_t ws_size,
                              hipStream_t stream) {
    const float* q = (const float*)d_in[0];
    const float* t = (const float*)d_in[1];
    char* ws = (char*)d_ws;

    char* bnq = ws;                                                    // 2 MB (must stay first)
    int*  pval = (int*)(ws + (size_t)N * 128);                         // 1 MB (also overshoot pad)
    float* bsum = (float*)(ws + (size_t)N * 128 + (size_t)RS * N * 4); // 16 KB

    knorm<<<dim3(N / 4), dim3(256), 0, stream>>>(t, bnq);
    kargmax<<<dim3(CT * RS), dim3(256), 0, stream>>>(bnq, pval);
    kloss<<<dim3(N / 4), dim3(256), 0, stream>>>(q, t, pval, bsum);
    kfinal<<<dim3(1), dim3(256), 0, stream>>>(bsum, (float*)d_out);
}

// Round 26
// 61.624 us; speedup vs baseline: 4.8976x; 1.0121x over previous
//
#include <hip/hip_runtime.h>
#include <hip/hip_bf16.h>
#include <limits.h>

#define N 16384
#define D 128
#define RS 16                        // row splits (1024 rows each)
#define CT 32                        // col tiles (N / 512)
#define ROWS_PER_SPLIT (N / RS)      // 1024
#define ITERS (ROWS_PER_SPLIT / 32)  // 32 iterations of 32 rows

typedef __attribute__((ext_vector_type(4))) int i32x4;
typedef __attribute__((ext_vector_type(16))) int i32x16;

// ---------------- Kernel A: quantize targets -> int8 (scale 127), row-major ----------------
__global__ __launch_bounds__(256) void knorm(const float* __restrict__ t,
                                             char* __restrict__ bnq) {
    const int lane = threadIdx.x & 63;
    const int row  = blockIdx.x * 4 + (threadIdx.x >> 6);
    const float2 v = *(const float2*)(t + (size_t)row * D + lane * 2);
    float ss = v.x * v.x + v.y * v.y;
#pragma unroll
    for (int m = 1; m <= 32; m <<= 1) ss += __shfl_xor(ss, m, 64);
    const float s127 = rsqrtf(ss) * 127.0f;
    char2 o;
    o.x = (char)__float2int_rn(v.x * s127);
    o.y = (char)__float2int_rn(v.y * s127);
    *(char2*)(bnq + (size_t)row * 128 + lane * 2) = o;
}

// ---------------- Kernel B: fused i8 bn @ bn^T (32x32x32) + EXACT-row argmax ----------------
// R23 core, ONE scheduling change: c4-OUTER COMPUTEF — each c4 is a self-
// contained {4-MFMA chain -> diag -> pack+max3}, so pack(c4=i) is independent
// of MFMAs(c4>i) and the scheduler can hide the ~28 pack ops per c4 under the
// later chains' MFMA pipe time (ks-outer serialized: all 16 MFMAs -> all pack).
// setprio dropped (GEMM-null, m190). No register growth.
__global__ __launch_bounds__(256, 2) void kargmax(const char* __restrict__ bnq,
                                                  int* __restrict__ pval) {
    const int tid  = threadIdx.x;
    const int lane = tid & 63;
    const int w    = tid >> 6;
    const int b    = blockIdx.x;
    const int s    = (b & 7) * 2 + ((b >> 3) & 1);   // 2 splits per XCD
    const int ct   = b >> 4;                          // 0..31
    const int j0w  = ct * 512 + w * 128;
    const int rbase = s * ROWS_PER_SPLIT;

    const int cl = lane & 31;      // row/col within 32
    const int hi = lane >> 5;      // k-half
    const int rloc = cl - 4 * hi;  // diag helper: diag when rloc == (r&3)+8*(r>>2)

    // persistent B fragments: 128 cols x 128 K, i8 (4 col-tiles x 4 K-steps, 64 VGPRs)
    i32x4 fb[4][4];
#pragma unroll
    for (int c4 = 0; c4 < 4; ++c4)
#pragma unroll
        for (int ks = 0; ks < 4; ++ks)
            fb[c4][ks] = *(const i32x4*)(bnq + (size_t)(j0w + c4 * 32 + cl) * 128 +
                                         ks * 32 + hi * 16);

    const char* aptr = bnq + (size_t)(rbase + cl) * 128 + hi * 16;

    int mv[4];
#pragma unroll
    for (int c4 = 0; c4 < 4; ++c4) mv[c4] = INT_MIN;

    const i32x16 z16 = {0,0,0,0,0,0,0,0,0,0,0,0,0,0,0,0};
    i32x4 fA[4], fB[4];

#define LOADF(buf, itv) do {                                  \
    const char* p_ = aptr + (size_t)(itv) * 4096;             \
    buf[0] = *(const i32x4*)(p_);                             \
    buf[1] = *(const i32x4*)(p_ + 32);                        \
    buf[2] = *(const i32x4*)(p_ + 64);                        \
    buf[3] = *(const i32x4*)(p_ + 96); } while (0)

#define COMPUTEF(buf, itv) do {                                                             \
    const int r0_ = rbase + (itv) * 32;                                                     \
    const bool dg_ = ((unsigned)(r0_ - j0w) < 128u);                                        \
    const int ib_ = (itv) * 32 + 4 * hi;                                                    \
    _Pragma("unroll")                                                                       \
    for (int c4 = 0; c4 < 4; ++c4) {                                                        \
        i32x16 acc;                                                                         \
        acc = __builtin_amdgcn_mfma_i32_32x32x32_i8(buf[0], fb[c4][0], z16, 0, 0, 0);       \
        acc = __builtin_amdgcn_mfma_i32_32x32x32_i8(buf[1], fb[c4][1], acc, 0, 0, 0);       \
        acc = __builtin_amdgcn_mfma_i32_32x32x32_i8(buf[2], fb[c4][2], acc, 0, 0, 0);       \
        acc = __builtin_amdgcn_mfma_i32_32x32x32_i8(buf[3], fb[c4][3], acc, 0, 0, 0);       \
        if (dg_ && r0_ == j0w + c4 * 32) {                                                  \
            _Pragma("unroll")                                                               \
            for (int r = 0; r < 16; ++r)                                                    \
                if (rloc == ((r & 3) + 8 * (r >> 2))) acc[r] = -(1 << 21);                  \
        }                                                                                   \
        int p[16];                                                                          \
        _Pragma("unroll")                                                                   \
        for (int r = 0; r < 16; ++r)                                                        \
            p[r] = (int)(((unsigned)acc[r] << 10)) +                                        \
                   (ib_ + (r & 3) + 8 * (r >> 2));                                          \
        const int a0 = max(max(p[0],  p[1]),  p[2]);                                        \
        const int a1 = max(max(p[3],  p[4]),  p[5]);                                        \
        const int a2 = max(max(p[6],  p[7]),  p[8]);                                        \
        const int a3 = max(max(p[9],  p[10]), p[11]);                                       \
        const int a4 = max(max(p[12], p[13]), p[14]);                                       \
        const int b0 = max(max(a0, a1), a2);                                                \
        const int b1 = max(max(a3, a4), p[15]);                                             \
        mv[c4] = max(mv[c4], max(b0, b1));                                                  \
    }                                                                                       \
    } while (0)

    LOADF(fA, 0);
    LOADF(fB, 1);
    for (int it2 = 0; it2 < ITERS; it2 += 2) {
        COMPUTEF(fA, it2);     LOADF(fA, it2 + 2);   // overshoot -> pval pad, unused
        COMPUTEF(fB, it2 + 1); LOADF(fB, it2 + 3);
    }
#undef LOADF
#undef COMPUTEF

    // lanes l and l+32 hold different row-halves of each column: one max merges them
#pragma unroll
    for (int c4 = 0; c4 < 4; ++c4) {
        int v = mv[c4];
        v = max(v, __shfl_xor(v, 32, 64));
        if (lane < 32)
            pval[(size_t)(j0w + c4 * 32 + cl) * RS + s] = v;
    }
}

// ---------------- Kernel C: merge splits (coalesced), hinge loss ----------------
__global__ __launch_bounds__(256) void kloss(const float* __restrict__ q,
                                             const float* __restrict__ t,
                                             const int* __restrict__ pval,
                                             float* __restrict__ bsum) {
    const int j    = blockIdx.x * 4 + (threadIdx.x >> 6);
    const int lane = threadIdx.x & 63;

    // merge the RS split winners — pval[j][s] is one contiguous 64B line
    int v = INT_MIN;
    int sidx = 0;
    if (lane < RS) { v = pval[(size_t)j * RS + lane]; sidx = lane; }
#pragma unroll
    for (int m = 1; m <= 8; m <<= 1) {
        const int ov = __shfl_xor(v, m, 64);
        const int os = __shfl_xor(sidx, m, 64);
        if (ov > v || (ov == v && os < sidx)) { v = ov; sidx = os; }
    }
    v = __shfl(v, 0, 64);
    sidx = __shfl(sidx, 0, 64);
    const int c = sidx * ROWS_PER_SPLIT + (v & 1023);   // exact winner row

    const float2 qv = *(const float2*)(q + (size_t)j * D + lane * 2);
    const float2 tv = *(const float2*)(t + (size_t)j * D + lane * 2);
    const float2 wv = *(const float2*)(t + (size_t)c * D + lane * 2);
    float qq = qv.x * qv.x + qv.y * qv.y;
    float tt = tv.x * tv.x + tv.y * tv.y;
    float ww = wv.x * wv.x + wv.y * wv.y;
    float qt = qv.x * tv.x + qv.y * tv.y;
    float qw = qv.x * wv.x + qv.y * wv.y;
#pragma unroll
    for (int m = 1; m <= 32; m <<= 1) {
        qq += __shfl_xor(qq, m, 64);
        tt += __shfl_xor(tt, m, 64);
        ww += __shfl_xor(ww, m, 64);
        qt += __shfl_xor(qt, m, 64);
        qw += __shfl_xor(qw, m, 64);
    }
    const float pos = qt * rsqrtf(qq * tt);
    const float neg = qw * rsqrtf(qq * ww);
    const float l = fmaxf(0.f, 1.0f - pos + neg);

    __shared__ float ls[4];
    if (lane == 0) ls[threadIdx.x >> 6] = l;
    __syncthreads();
    if (threadIdx.x == 0) bsum[blockIdx.x] = ls[0] + ls[1] + ls[2] + ls[3];
}

// ---------------- Kernel D: deterministic final mean ----------------
__global__ __launch_bounds__(256) void kfinal(const float* __restrict__ bsum,
                                              float* __restrict__ out) {
    float sum = 0.f;
    for (int i = threadIdx.x; i < N / 4; i += 256) sum += bsum[i];
#pragma unroll
    for (int m = 1; m <= 32; m <<= 1) sum += __shfl_xor(sum, m, 64);
    __shared__ float ws2[4];
    if ((threadIdx.x & 63) == 0) ws2[threadIdx.x >> 6] = sum;
    __syncthreads();
    if (threadIdx.x == 0) out[0] = (ws2[0] + ws2[1] + ws2[2] + ws2[3]) * (1.0f / N);
}

extern "C" void kernel_launch(void* const* d_in, const int* in_sizes, int n_in,
                              void* d_out, int out_size, void* d_ws, size_t ws_size,
                              hipStream_t stream) {
    const float* q = (const float*)d_in[0];
    const float* t = (const float*)d_in[1];
    char* ws = (char*)d_ws;

    char* bnq = ws;                                                    // 2 MB (must stay first)
    int*  pval = (int*)(ws + (size_t)N * 128);                         // 1 MB (also overshoot pad)
    float* bsum = (float*)(ws + (size_t)N * 128 + (size_t)RS * N * 4); // 16 KB

    knorm<<<dim3(N / 4), dim3(256), 0, stream>>>(t, bnq);
    kargmax<<<dim3(CT * RS), dim3(256), 0, stream>>>(bnq, pval);
    kloss<<<dim3(N / 4), dim3(256), 0, stream>>>(q, t, pval, bsum);
    kfinal<<<dim3(1), dim3(256), 0, stream>>>(bsum, (float*)d_out);
}